// Round 2
// baseline (449.247 us; speedup 1.0000x reference)
//
#include <hip/hip_runtime.h>
#include <hip/hip_bf16.h>
#include <cstdint>
#include <cstddef>

#define N_NODES 50000
#define N_EDGES 300000
#define DIM     256
#define KTOT    768   // concatenated K: [agg*norm | h | prev_h]

typedef unsigned short u16;
typedef __attribute__((ext_vector_type(8))) short short8v;   // 8 bf16 = 4 VGPRs (MFMA A/B frag)
typedef __attribute__((ext_vector_type(4))) float float4v;   // MFMA C/D frag

static __device__ __forceinline__ u16 f2bf(float f) {
    union { float f; unsigned u; } v; v.f = f;
    unsigned u = v.u;
    unsigned r = u + 0x7FFFu + ((u >> 16) & 1u);  // RNE
    return (u16)(r >> 16);
}

// ---------------- K1: h, prev_h -> bf16 ----------------
__global__ void conv_kernel(const float* __restrict__ h, const float* __restrict__ ph,
                            u16* __restrict__ Xh, u16* __restrict__ Xp) {
    int i = blockIdx.x * blockDim.x + threadIdx.x;   // 3.2M threads, 8 elems each
    int e0 = i * 8;
    if (e0 >= 2 * N_NODES * DIM) return;
    const float* src; u16* dst; int off;
    if (e0 < N_NODES * DIM) { src = h;  dst = Xh; off = e0; }
    else                    { src = ph; dst = Xp; off = e0 - N_NODES * DIM; }
    float4 a = *(const float4*)(src + off);
    float4 b = *(const float4*)(src + off + 4);
    u16 o[8] = { f2bf(a.x), f2bf(a.y), f2bf(a.z), f2bf(a.w),
                 f2bf(b.x), f2bf(b.y), f2bf(b.z), f2bf(b.w) };
    *(uint4*)(dst + off) = *(const uint4*)o;
}

// ---------------- K2: build Wt[d][k] = Wseg[k%256][d] (bf16, B^T layout) ----------------
__global__ void wt_kernel(const float* __restrict__ Wn, const float* __restrict__ Wl,
                          const float* __restrict__ Wsc, u16* __restrict__ Wt) {
    int k = blockIdx.x;    // 0..767
    int d = threadIdx.x;   // 0..255
    const float* W = (k < 256) ? Wn : ((k < 512) ? Wl : Wsc);
    int kk = k & 255;
    Wt[(size_t)d * KTOT + k] = f2bf(W[kk * DIM + d]);
}

// ---------------- K3: in-degree histogram ----------------
__global__ void hist_kernel(const int* __restrict__ dstv, int* __restrict__ deg) {
    int e = blockIdx.x * 256 + threadIdx.x;
    if (e < N_EDGES) atomicAdd(&deg[dstv[e]], 1);
}

// ---------------- K4: exclusive scan (1 block) -> offsets[N+1], cursor ----------------
__global__ void scan_kernel(const int* __restrict__ deg, int* __restrict__ offsets,
                            int* __restrict__ cursor) {
    __shared__ int sdata[1024];
    int t = threadIdx.x;
    const int CH = (N_NODES + 1023) / 1024;  // 49
    int base = t * CH;
    int hi = min(base + CH, N_NODES);
    int sum = 0;
    for (int i = base; i < hi; i++) sum += deg[i];
    sdata[t] = sum;
    __syncthreads();
    for (int off = 1; off < 1024; off <<= 1) {
        int v = (t >= off) ? sdata[t - off] : 0;
        __syncthreads();
        sdata[t] += v;
        __syncthreads();
    }
    int run = sdata[t] - sum;  // exclusive base
    for (int i = base; i < hi; i++) {
        offsets[i] = run; cursor[i] = run; run += deg[i];
    }
    if (t == 1023) offsets[N_NODES] = sdata[1023];
}

// ---------------- K5: scatter edges into CSR slots ----------------
__global__ void scatter_kernel(const int* __restrict__ src, const int* __restrict__ dstv,
                               const int* __restrict__ et, int* __restrict__ cursor,
                               int* __restrict__ es, int* __restrict__ ee) {
    int e = blockIdx.x * 256 + threadIdx.x;
    if (e >= N_EDGES) return;
    int d = dstv[e];
    int pos = atomicAdd(&cursor[d], 1);
    es[pos] = src[e];
    ee[pos] = et[e];
}

// ---------------- K6: wave-per-node gather-reduce -> Xa = bf16(agg*norm); worklist ----------------
__global__ void agg_kernel(const float* __restrict__ h, const float* __restrict__ emb,
                           const float* __restrict__ norm, const int* __restrict__ offsets,
                           const int* __restrict__ es, const int* __restrict__ ee,
                           u16* __restrict__ Xa, int* __restrict__ wl_count, int* __restrict__ wl) {
    int wave = (blockIdx.x * 256 + threadIdx.x) >> 6;
    int lane = threadIdx.x & 63;
    if (wave >= N_NODES) return;
    int n = wave;
    int s0 = offsets[n], s1 = offsets[n + 1];
    int c4 = lane * 4;
    float4 acc = make_float4(0.f, 0.f, 0.f, 0.f);
    for (int e = s0; e < s1; e++) {
        int s = es[e], t = ee[e];
        float4 hv = *(const float4*)(h   + (size_t)s * DIM + c4);
        float4 ev = *(const float4*)(emb + (size_t)t * DIM + c4);
        acc.x += hv.x + ev.x; acc.y += hv.y + ev.y;
        acc.z += hv.z + ev.z; acc.w += hv.w + ev.w;
    }
    float nr = norm[n];
    u16 o[4] = { f2bf(acc.x * nr), f2bf(acc.y * nr), f2bf(acc.z * nr), f2bf(acc.w * nr) };
    *(ushort4*)(Xa + (size_t)n * DIM + c4) = *(const ushort4*)o;
    if (lane == 0 && s1 == s0) { int idx = atomicAdd(wl_count, 1); wl[idx] = n; }
}

// ---------------- K7: fused MFMA GEMM + epilogue ----------------
// Block: 256 thr = 4 waves. Tile: 64 nodes x 256 cols (wave w: cols [w*64, w*64+64)).
// K loop: kt 0..11 over [Xa(0..255) | Xh(256..511) | Xp(512..767)] vs Wt rows.
// acc1 accumulates kt 0..7 (agg*norm@Wn + h@Wl), acc2 kt 8..11 (prev_h@Wsc).
#define LDSP 72   // 64 + 8 bf16 pad: row stride 144B -> 2-way bank aliasing (free)
__launch_bounds__(256, 2)
__global__ void gemm_kernel(const u16* __restrict__ Xa, const u16* __restrict__ Xh,
                            const u16* __restrict__ Xp, const u16* __restrict__ Wt,
                            const float* __restrict__ prev_h, const float* __restrict__ bias,
                            float* __restrict__ out) {
    __shared__ u16 Xs[64 * LDSP];
    __shared__ u16 Ws[256 * LDSP];
    int tid = threadIdx.x;
    int wave = tid >> 6, lane = tid & 63, q = lane >> 4, m16 = lane & 15;
    int m0 = blockIdx.x * 64;

    float4v acc1[4][4], acc2[4][4];
#pragma unroll
    for (int i = 0; i < 4; i++)
#pragma unroll
        for (int j = 0; j < 4; j++) { acc1[i][j] = (float4v)0.f; acc2[i][j] = (float4v)0.f; }

    // staging maps
    // X: 64 rows x 64 cols bf16 = 4096 elems; 256 thr x 2 x uint4(8 elems).
    int xr = tid >> 3, xc = (tid & 7) * 8;        // rows 0..31 (+32 for 2nd), cols 0..56
    int wp = tid & 7, wd = tid >> 3;              // W: 8x16B per row, 32 rows/pass
    int xrow0 = min(m0 + xr, N_NODES - 1);
    int xrow1 = min(m0 + xr + 32, N_NODES - 1);

    for (int kt = 0; kt < 12; kt++) {
        const u16* Xsrc = (kt < 4) ? Xa : ((kt < 8) ? Xh : Xp);
        int koff = (kt & 3) * 64;
        *(uint4*)(&Xs[xr * LDSP + xc]) =
            *(const uint4*)(Xsrc + (size_t)xrow0 * DIM + koff + xc);
        *(uint4*)(&Xs[(xr + 32) * LDSP + xc]) =
            *(const uint4*)(Xsrc + (size_t)xrow1 * DIM + koff + xc);
#pragma unroll
        for (int it = 0; it < 8; it++) {
            int d = wd + it * 32;
            *(uint4*)(&Ws[d * LDSP + wp * 8]) =
                *(const uint4*)(Wt + (size_t)d * KTOT + kt * 64 + wp * 8);
        }
        __syncthreads();
#pragma unroll
        for (int kk = 0; kk < 2; kk++) {
            short8v af[4], bfr[4];
#pragma unroll
            for (int mi = 0; mi < 4; mi++)
                af[mi] = *(const short8v*)(&Xs[(mi * 16 + m16) * LDSP + kk * 32 + q * 8]);
#pragma unroll
            for (int ni = 0; ni < 4; ni++)
                bfr[ni] = *(const short8v*)(&Ws[(wave * 64 + ni * 16 + m16) * LDSP + kk * 32 + q * 8]);
            if (kt < 8) {
#pragma unroll
                for (int mi = 0; mi < 4; mi++)
#pragma unroll
                    for (int ni = 0; ni < 4; ni++)
                        acc1[mi][ni] = __builtin_amdgcn_mfma_f32_16x16x32_bf16(
                            af[mi], bfr[ni], acc1[mi][ni], 0, 0, 0);
            } else {
#pragma unroll
                for (int mi = 0; mi < 4; mi++)
#pragma unroll
                    for (int ni = 0; ni < 4; ni++)
                        acc2[mi][ni] = __builtin_amdgcn_mfma_f32_16x16x32_bf16(
                            af[mi], bfr[ni], acc2[mi][ni], 0, 0, 0);
            }
        }
        __syncthreads();
    }

    // epilogue: C/D layout col=lane&15, row=q*4+reg  [measured m89]
#pragma unroll
    for (int mi = 0; mi < 4; mi++) {
#pragma unroll
        for (int ni = 0; ni < 4; ni++) {
            int d = wave * 64 + ni * 16 + m16;
            float b = bias[d];
#pragma unroll
            for (int r = 0; r < 4; r++) {
                int node = m0 + mi * 16 + q * 4 + r;
                if (node < N_NODES) {
                    float S  = acc2[mi][ni][r] + b;
                    float sw = 1.f / (1.f + __expf(-S));
                    float ph = prev_h[(size_t)node * DIM + d];
                    float v  = sw * acc1[mi][ni][r] + (1.f - sw) * ph;
                    out[(size_t)node * DIM + d] = fmaxf(v, 0.f);
                }
            }
        }
    }
}

// ---------------- K8: fixup for in_deg==0 nodes (evolve_loop_weight path, exact fp32) --------
__global__ void fixup_kernel(const float* __restrict__ h, const float* __restrict__ prev_h,
                             const float* __restrict__ We, const float* __restrict__ Wsc,
                             const float* __restrict__ bias, const int* __restrict__ wl_count,
                             const int* __restrict__ wl, float* __restrict__ out) {
    __shared__ float ph[DIM], hh[DIM];
    int d = threadIdx.x;
    int cnt = *wl_count;
    for (int i = blockIdx.x; i < cnt; i += gridDim.x) {
        int n = wl[i];
        ph[d] = prev_h[(size_t)n * DIM + d];
        hh[d] = h[(size_t)n * DIM + d];
        __syncthreads();
        float s = 0.f, l = 0.f;
        for (int k = 0; k < DIM; k++) {
            s += ph[k] * Wsc[k * DIM + d];
            l += hh[k] * We[k * DIM + d];
        }
        float sw = 1.f / (1.f + __expf(-(s + bias[d])));
        float v = sw * l + (1.f - sw) * ph[d];
        out[(size_t)n * DIM + d] = fmaxf(v, 0.f);
        __syncthreads();
    }
}

extern "C" void kernel_launch(void* const* d_in, const int* in_sizes, int n_in,
                              void* d_out, int out_size, void* d_ws, size_t ws_size,
                              hipStream_t stream) {
    const float* h      = (const float*)d_in[0];
    const float* prev_h = (const float*)d_in[1];
    const float* emb    = (const float*)d_in[2];
    const float* norm   = (const float*)d_in[3];
    const float* Wn     = (const float*)d_in[4];
    const float* Wl     = (const float*)d_in[5];
    const float* We     = (const float*)d_in[6];
    const float* Wsc    = (const float*)d_in[7];
    const float* bias   = (const float*)d_in[8];
    const int*   src    = (const int*)d_in[9];
    const int*   dstv   = (const int*)d_in[10];
    const int*   et     = (const int*)d_in[11];
    float* out = (float*)d_out;

    char* ws = (char*)d_ws;
    size_t off = 0;
    auto alloc = [&](size_t bytes) -> char* {
        char* p = ws + off; off += (bytes + 255) & ~(size_t)255; return p;
    };
    u16* Xa      = (u16*)alloc((size_t)N_NODES * DIM * 2);
    u16* Xh      = (u16*)alloc((size_t)N_NODES * DIM * 2);
    u16* Xp      = (u16*)alloc((size_t)N_NODES * DIM * 2);
    u16* Wt      = (u16*)alloc((size_t)DIM * KTOT * 2);
    int* deg     = (int*)alloc((size_t)N_NODES * 4);
    int* wlcnt   = (int*)alloc(16);
    int* wl      = (int*)alloc((size_t)N_NODES * 4);
    int* offsets = (int*)alloc((size_t)(N_NODES + 1) * 4);
    int* cursor  = (int*)alloc((size_t)N_NODES * 4);
    int* es      = (int*)alloc((size_t)N_EDGES * 4);
    int* ee      = (int*)alloc((size_t)N_EDGES * 4);

    hipMemsetAsync(deg, 0, (size_t)N_NODES * 4, stream);
    hipMemsetAsync(wlcnt, 0, 4, stream);

    conv_kernel<<<(2 * N_NODES * DIM / 8 + 255) / 256, 256, 0, stream>>>(h, prev_h, Xh, Xp);
    wt_kernel<<<KTOT, 256, 0, stream>>>(Wn, Wl, Wsc, Wt);
    hist_kernel<<<(N_EDGES + 255) / 256, 256, 0, stream>>>(dstv, deg);
    scan_kernel<<<1, 1024, 0, stream>>>(deg, offsets, cursor);
    scatter_kernel<<<(N_EDGES + 255) / 256, 256, 0, stream>>>(src, dstv, et, cursor, es, ee);
    agg_kernel<<<(N_NODES + 3) / 4, 256, 0, stream>>>(h, emb, norm, offsets, es, ee, Xa, wlcnt, wl);
    gemm_kernel<<<(N_NODES + 63) / 64, 256, 0, stream>>>(Xa, Xh, Xp, Wt, prev_h, bias, out);
    fixup_kernel<<<256, 256, 0, stream>>>(h, prev_h, We, Wsc, bias, wlcnt, wl, out);
}

// Round 3
// 353.217 us; speedup vs baseline: 1.2719x; 1.2719x over previous
//
#include <hip/hip_runtime.h>
#include <hip/hip_bf16.h>
#include <cstdint>
#include <cstddef>

#define N_NODES 50000
#define N_EDGES 300000
#define DIM     256
#define KTOT    768   // concatenated K: [agg*norm | h | prev_h]

#define SCAN_BLK  256
#define SCAN_NBLK ((N_NODES + SCAN_BLK - 1) / SCAN_BLK)   // 196

typedef unsigned short u16;
typedef __attribute__((ext_vector_type(8))) short short8v;   // 8 bf16 = 4 VGPRs (MFMA A/B frag)
typedef __attribute__((ext_vector_type(4))) float float4v;   // MFMA C/D frag

static __device__ __forceinline__ u16 f2bf(float f) {
    union { float f; unsigned u; } v; v.f = f;
    unsigned u = v.u;
    unsigned r = u + 0x7FFFu + ((u >> 16) & 1u);  // RNE
    return (u16)(r >> 16);
}

// ---------------- K1: h, prev_h -> bf16 ----------------
__global__ void conv_kernel(const float* __restrict__ h, const float* __restrict__ ph,
                            u16* __restrict__ Xh, u16* __restrict__ Xp) {
    int i = blockIdx.x * blockDim.x + threadIdx.x;   // 1.6M threads, 8 elems each
    int e0 = i * 8;
    if (e0 >= 2 * N_NODES * DIM) return;
    const float* src; u16* dst; int off;
    if (e0 < N_NODES * DIM) { src = h;  dst = Xh; off = e0; }
    else                    { src = ph; dst = Xp; off = e0 - N_NODES * DIM; }
    float4 a = *(const float4*)(src + off);
    float4 b = *(const float4*)(src + off + 4);
    u16 o[8] = { f2bf(a.x), f2bf(a.y), f2bf(a.z), f2bf(a.w),
                 f2bf(b.x), f2bf(b.y), f2bf(b.z), f2bf(b.w) };
    *(uint4*)(dst + off) = *(const uint4*)o;
}

// ---------------- K2: build Wt[d][k] = Wseg[k%256][d] (bf16, B^T layout) ----------------
__global__ void wt_kernel(const float* __restrict__ Wn, const float* __restrict__ Wl,
                          const float* __restrict__ Wsc, u16* __restrict__ Wt) {
    int k = blockIdx.x;    // 0..767
    int d = threadIdx.x;   // 0..255
    const float* W = (k < 256) ? Wn : ((k < 512) ? Wl : Wsc);
    int kk = k & 255;
    Wt[(size_t)d * KTOT + k] = f2bf(W[kk * DIM + d]);
}

// ---------------- K3: in-degree histogram ----------------
__global__ void hist_kernel(const int* __restrict__ dstv, int* __restrict__ deg) {
    int e = blockIdx.x * 256 + threadIdx.x;
    if (e < N_EDGES) atomicAdd(&deg[dstv[e]], 1);
}

// ---------------- K4a: per-block scan of deg ----------------
__global__ void scanA_kernel(const int* __restrict__ deg, int* __restrict__ excl_local,
                             int* __restrict__ block_sum) {
    __shared__ int sdata[SCAN_BLK];
    int t = threadIdx.x, i = blockIdx.x * SCAN_BLK + t;
    int v = (i < N_NODES) ? deg[i] : 0;
    sdata[t] = v;
    __syncthreads();
    for (int off = 1; off < SCAN_BLK; off <<= 1) {
        int u = (t >= off) ? sdata[t - off] : 0;
        __syncthreads();
        sdata[t] += u;
        __syncthreads();
    }
    if (i < N_NODES) excl_local[i] = sdata[t] - v;
    if (t == SCAN_BLK - 1) block_sum[blockIdx.x] = sdata[t];
}

// ---------------- K4b: scan 196 block sums (1 block) ----------------
__global__ void scanB_kernel(const int* __restrict__ block_sum, int* __restrict__ block_base,
                             int* __restrict__ offsets) {
    __shared__ int sdata[SCAN_NBLK];
    int t = threadIdx.x;
    int v = (t < SCAN_NBLK) ? block_sum[t] : 0;
    if (t < SCAN_NBLK) sdata[t] = v;
    __syncthreads();
    for (int off = 1; off < SCAN_NBLK; off <<= 1) {
        int u = (t >= off && t < SCAN_NBLK) ? sdata[t - off] : 0;
        __syncthreads();
        if (t < SCAN_NBLK) sdata[t] += u;
        __syncthreads();
    }
    if (t < SCAN_NBLK) block_base[t] = sdata[t] - v;
    if (t == SCAN_NBLK - 1) offsets[N_NODES] = sdata[t];
}

// ---------------- K4c: combine -> offsets, cursor ----------------
__global__ void scanC_kernel(const int* __restrict__ excl_local, const int* __restrict__ block_base,
                             int* __restrict__ offsets, int* __restrict__ cursor) {
    int i = blockIdx.x * SCAN_BLK + threadIdx.x;
    if (i < N_NODES) {
        int e = block_base[blockIdx.x] + excl_local[i];
        offsets[i] = e; cursor[i] = e;
    }
}

// ---------------- K5: scatter edges into CSR slots ----------------
__global__ void scatter_kernel(const int* __restrict__ src, const int* __restrict__ dstv,
                               const int* __restrict__ et, int* __restrict__ cursor,
                               int* __restrict__ es, int* __restrict__ ee) {
    int e = blockIdx.x * 256 + threadIdx.x;
    if (e >= N_EDGES) return;
    int d = dstv[e];
    int pos = atomicAdd(&cursor[d], 1);
    es[pos] = src[e];
    ee[pos] = et[e];
}

// ---------------- K6: wave-per-node gather-reduce -> Xa = bf16(agg*norm); worklist ----------------
__global__ void agg_kernel(const float* __restrict__ h, const float* __restrict__ emb,
                           const float* __restrict__ norm, const int* __restrict__ offsets,
                           const int* __restrict__ es, const int* __restrict__ ee,
                           u16* __restrict__ Xa, int* __restrict__ wl_count, int* __restrict__ wl) {
    int wave = (blockIdx.x * 256 + threadIdx.x) >> 6;
    int lane = threadIdx.x & 63;
    if (wave >= N_NODES) return;
    int n = wave;
    int s0 = offsets[n], s1 = offsets[n + 1];
    int c4 = lane * 4;
    float4 acc = make_float4(0.f, 0.f, 0.f, 0.f);
    for (int e = s0; e < s1; e++) {
        int s = es[e], t = ee[e];
        float4 hv = *(const float4*)(h   + (size_t)s * DIM + c4);
        float4 ev = *(const float4*)(emb + (size_t)t * DIM + c4);
        acc.x += hv.x + ev.x; acc.y += hv.y + ev.y;
        acc.z += hv.z + ev.z; acc.w += hv.w + ev.w;
    }
    float nr = norm[n];
    u16 o[4] = { f2bf(acc.x * nr), f2bf(acc.y * nr), f2bf(acc.z * nr), f2bf(acc.w * nr) };
    *(ushort4*)(Xa + (size_t)n * DIM + c4) = *(const ushort4*)o;
    if (lane == 0 && s1 == s0) { int idx = atomicAdd(wl_count, 1); wl[idx] = n; }
}

// ---------------- K7: fused MFMA GEMM + epilogue ----------------
// Block: 256 thr = 4 waves. Tile: 64 nodes x 256 cols (wave w: cols [w*64, w*64+64)).
// K loop: kt 0..11 over [Xa(0..255) | Xh(256..511) | Xp(512..767)] vs Wt rows.
// acc1 accumulates kt 0..7 (agg*norm@Wn + h@Wl), acc2 kt 8..11 (prev_h@Wsc).
#define LDSP 72   // 64 + 8 bf16 pad: row stride 144B -> 2-way bank aliasing (free)
__launch_bounds__(256, 2)
__global__ void gemm_kernel(const u16* __restrict__ Xa, const u16* __restrict__ Xh,
                            const u16* __restrict__ Xp, const u16* __restrict__ Wt,
                            const float* __restrict__ prev_h, const float* __restrict__ bias,
                            float* __restrict__ out) {
    __shared__ u16 Xs[64 * LDSP];
    __shared__ u16 Ws[256 * LDSP];
    int tid = threadIdx.x;
    int wave = tid >> 6, lane = tid & 63, q = lane >> 4, m16 = lane & 15;
    int m0 = blockIdx.x * 64;

    float4v acc1[4][4], acc2[4][4];
#pragma unroll
    for (int i = 0; i < 4; i++)
#pragma unroll
        for (int j = 0; j < 4; j++) { acc1[i][j] = (float4v)0.f; acc2[i][j] = (float4v)0.f; }

    // staging maps
    // X: 64 rows x 64 cols bf16 = 4096 elems; 256 thr x 2 x uint4(8 elems).
    int xr = tid >> 3, xc = (tid & 7) * 8;        // rows 0..31 (+32 for 2nd), cols 0..56
    int wp = tid & 7, wd = tid >> 3;              // W: 8x16B per row, 32 rows/pass
    int xrow0 = min(m0 + xr, N_NODES - 1);
    int xrow1 = min(m0 + xr + 32, N_NODES - 1);

    for (int kt = 0; kt < 12; kt++) {
        const u16* Xsrc = (kt < 4) ? Xa : ((kt < 8) ? Xh : Xp);
        int koff = (kt & 3) * 64;
        *(uint4*)(&Xs[xr * LDSP + xc]) =
            *(const uint4*)(Xsrc + (size_t)xrow0 * DIM + koff + xc);
        *(uint4*)(&Xs[(xr + 32) * LDSP + xc]) =
            *(const uint4*)(Xsrc + (size_t)xrow1 * DIM + koff + xc);
#pragma unroll
        for (int it = 0; it < 8; it++) {
            int d = wd + it * 32;
            *(uint4*)(&Ws[d * LDSP + wp * 8]) =
                *(const uint4*)(Wt + (size_t)d * KTOT + kt * 64 + wp * 8);
        }
        __syncthreads();
#pragma unroll
        for (int kk = 0; kk < 2; kk++) {
            short8v af[4], bfr[4];
#pragma unroll
            for (int mi = 0; mi < 4; mi++)
                af[mi] = *(const short8v*)(&Xs[(mi * 16 + m16) * LDSP + kk * 32 + q * 8]);
#pragma unroll
            for (int ni = 0; ni < 4; ni++)
                bfr[ni] = *(const short8v*)(&Ws[(wave * 64 + ni * 16 + m16) * LDSP + kk * 32 + q * 8]);
            if (kt < 8) {
#pragma unroll
                for (int mi = 0; mi < 4; mi++)
#pragma unroll
                    for (int ni = 0; ni < 4; ni++)
                        acc1[mi][ni] = __builtin_amdgcn_mfma_f32_16x16x32_bf16(
                            af[mi], bfr[ni], acc1[mi][ni], 0, 0, 0);
            } else {
#pragma unroll
                for (int mi = 0; mi < 4; mi++)
#pragma unroll
                    for (int ni = 0; ni < 4; ni++)
                        acc2[mi][ni] = __builtin_amdgcn_mfma_f32_16x16x32_bf16(
                            af[mi], bfr[ni], acc2[mi][ni], 0, 0, 0);
            }
        }
        __syncthreads();
    }

    // epilogue: C/D layout col=lane&15, row=q*4+reg  [measured m89]
#pragma unroll
    for (int mi = 0; mi < 4; mi++) {
#pragma unroll
        for (int ni = 0; ni < 4; ni++) {
            int d = wave * 64 + ni * 16 + m16;
            float b = bias[d];
#pragma unroll
            for (int r = 0; r < 4; r++) {
                int node = m0 + mi * 16 + q * 4 + r;
                if (node < N_NODES) {
                    float S  = acc2[mi][ni][r] + b;
                    float sw = 1.f / (1.f + __expf(-S));
                    float ph = prev_h[(size_t)node * DIM + d];
                    float v  = sw * acc1[mi][ni][r] + (1.f - sw) * ph;
                    out[(size_t)node * DIM + d] = fmaxf(v, 0.f);
                }
            }
        }
    }
}

// ---------------- K8: fixup for in_deg==0 nodes (evolve_loop_weight path, exact fp32) --------
__global__ void fixup_kernel(const float* __restrict__ h, const float* __restrict__ prev_h,
                             const float* __restrict__ We, const float* __restrict__ Wsc,
                             const float* __restrict__ bias, const int* __restrict__ wl_count,
                             const int* __restrict__ wl, float* __restrict__ out) {
    __shared__ float ph[DIM], hh[DIM];
    int d = threadIdx.x;
    int cnt = *wl_count;
    for (int i = blockIdx.x; i < cnt; i += gridDim.x) {
        int n = wl[i];
        ph[d] = prev_h[(size_t)n * DIM + d];
        hh[d] = h[(size_t)n * DIM + d];
        __syncthreads();
        float s = 0.f, l = 0.f;
        for (int k = 0; k < DIM; k++) {
            s += ph[k] * Wsc[k * DIM + d];
            l += hh[k] * We[k * DIM + d];
        }
        float sw = 1.f / (1.f + __expf(-(s + bias[d])));
        float v = sw * l + (1.f - sw) * ph[d];
        out[(size_t)n * DIM + d] = fmaxf(v, 0.f);
        __syncthreads();
    }
}

extern "C" void kernel_launch(void* const* d_in, const int* in_sizes, int n_in,
                              void* d_out, int out_size, void* d_ws, size_t ws_size,
                              hipStream_t stream) {
    const float* h      = (const float*)d_in[0];
    const float* prev_h = (const float*)d_in[1];
    const float* emb    = (const float*)d_in[2];
    const float* norm   = (const float*)d_in[3];
    const float* Wn     = (const float*)d_in[4];
    const float* Wl     = (const float*)d_in[5];
    const float* We     = (const float*)d_in[6];
    const float* Wsc    = (const float*)d_in[7];
    const float* bias   = (const float*)d_in[8];
    const int*   src    = (const int*)d_in[9];
    const int*   dstv   = (const int*)d_in[10];
    const int*   et     = (const int*)d_in[11];
    float* out = (float*)d_out;

    char* ws = (char*)d_ws;
    size_t off = 0;
    auto alloc = [&](size_t bytes) -> char* {
        char* p = ws + off; off += (bytes + 255) & ~(size_t)255; return p;
    };
    u16* Xa      = (u16*)alloc((size_t)N_NODES * DIM * 2);
    u16* Xh      = (u16*)alloc((size_t)N_NODES * DIM * 2);
    u16* Xp      = (u16*)alloc((size_t)N_NODES * DIM * 2);
    u16* Wt      = (u16*)alloc((size_t)DIM * KTOT * 2);
    int* deg     = (int*)alloc((size_t)N_NODES * 4);
    int* wlcnt   = (int*)alloc(16);
    int* wl      = (int*)alloc((size_t)N_NODES * 4);
    int* offsets = (int*)alloc((size_t)(N_NODES + 1) * 4);
    int* cursor  = (int*)alloc((size_t)N_NODES * 4);
    int* es      = (int*)alloc((size_t)N_EDGES * 4);
    int* ee      = (int*)alloc((size_t)N_EDGES * 4);
    int* excl    = (int*)alloc((size_t)N_NODES * 4);
    int* bsum    = (int*)alloc((size_t)SCAN_NBLK * 4);
    int* bbase   = (int*)alloc((size_t)SCAN_NBLK * 4);

    hipMemsetAsync(deg, 0, (size_t)N_NODES * 4, stream);
    hipMemsetAsync(wlcnt, 0, 4, stream);

    conv_kernel<<<(2 * N_NODES * DIM / 8 + 255) / 256, 256, 0, stream>>>(h, prev_h, Xh, Xp);
    wt_kernel<<<KTOT, 256, 0, stream>>>(Wn, Wl, Wsc, Wt);
    hist_kernel<<<(N_EDGES + 255) / 256, 256, 0, stream>>>(dstv, deg);
    scanA_kernel<<<SCAN_NBLK, SCAN_BLK, 0, stream>>>(deg, excl, bsum);
    scanB_kernel<<<1, SCAN_BLK, 0, stream>>>(bsum, bbase, offsets);
    scanC_kernel<<<SCAN_NBLK, SCAN_BLK, 0, stream>>>(excl, bbase, offsets, cursor);
    scatter_kernel<<<(N_EDGES + 255) / 256, 256, 0, stream>>>(src, dstv, et, cursor, es, ee);
    agg_kernel<<<(N_NODES + 3) / 4, 256, 0, stream>>>(h, emb, norm, offsets, es, ee, Xa, wlcnt, wl);
    gemm_kernel<<<(N_NODES + 63) / 64, 256, 0, stream>>>(Xa, Xh, Xp, Wt, prev_h, bias, out);
    fixup_kernel<<<256, 256, 0, stream>>>(h, prev_h, We, Wsc, bias, wlcnt, wl, out);
}